// Round 6
// baseline (422.413 us; speedup 1.0000x reference)
//
#include <hip/hip_runtime.h>

#define M_DIM 4096
#define K_DIM 16384
#define N_DIM 256
#define SPLIT 8
#define BK 64
#define BM 32
#define KSLICE (K_DIM / SPLIT)
#define NITER (KSLICE / BK)  // 32

typedef __bf16 bf16x8 __attribute__((ext_vector_type(8)));
typedef __bf16 bf16x4 __attribute__((ext_vector_type(4)));
typedef float f32x4 __attribute__((ext_vector_type(4)));

// ---------------- W transpose + convert: Wt[n][k] = bf16(W[k][n]) ----------------
__global__ __launch_bounds__(256) void wt_kernel(const float* __restrict__ W,
                                                 __bf16* __restrict__ Wt) {
  __shared__ float tile[64][65];
  const int k0 = blockIdx.x * 64, n0 = blockIdx.y * 64;
  const int t = threadIdx.x;
#pragma unroll
  for (int r = 0; r < 4; ++r) {
    int idx4 = r * 256 + t;
    int kr = idx4 >> 4, c4 = idx4 & 15;
    f32x4 v = *(const f32x4*)(W + (size_t)(k0 + kr) * N_DIM + n0 + c4 * 4);
#pragma unroll
    for (int j = 0; j < 4; ++j) tile[kr][c4 * 4 + j] = v[j];
  }
  __syncthreads();
#pragma unroll
  for (int r = 0; r < 4; ++r) {
    int nr = (t >> 4) + r * 16, k4 = t & 15;
    bf16x4 o;
#pragma unroll
    for (int j = 0; j < 4; ++j) o[j] = (__bf16)tile[k4 * 4 + j][nr];
    *(bf16x4*)(Wt + (size_t)(n0 + nr) * K_DIM + k0 + k4 * 4) = o;
  }
}

// ---------------- Main MFMA GEMM: round-5 structure, BM=32 for 3 blocks/CU ---------
// BM=32, BN=256, BK=64, 256 thr = 4 waves; wave w owns 32m x 64n at n=w*64
// (2x4 tiles of mfma_f32_16x16x32_bf16). Same 2-phase loop as the round-5 winner.
// LDS = As 32x72 (4.5 KiB) + Bs 256x72 (36 KiB) = 40.5 KiB -> 3 blocks/CU.
// Grid 1024 (128 m-blocks x 8 splits): 3 co-resident blocks/CU from different
// dispatch rounds -> decorrelated phases; one block's barrier drain is covered by
// the other two blocks' MFMA/load phases (m114 mechanism). HBM traffic identical
// to round 5 (disjoint x rows, same partials); only B's L2 re-read doubles.
// XCD pin (T1, protected): split = bid & 7, 1024 % 8 == 0 -> bijective.
__global__ __launch_bounds__(256, 3) void gemm_kernel(const float* __restrict__ x,
                                                      const __bf16* __restrict__ Wt,
                                                      __bf16* __restrict__ part) {
  __shared__ __bf16 As[BM * 72];
  __shared__ __bf16 Bs[256 * 72];

  const int t = threadIdx.x;
  const int l = t & 63;
  const int w = t >> 6;
  const int la = l & 15, q = l >> 4;
  const int bid = blockIdx.x;
  const int ysplit = bid & 7;           // -> XCD ysplit (round-robin dispatch)
  const int m0 = (bid >> 3) * BM;
  const int kbase = ysplit * KSLICE;

  // A staging: 2 float4/thread covering 32 rows x 64 k (8 threads per row-half)
  const int arow = t >> 3, ac4 = t & 7;
  // B staging: 8 x 16B/thread covering 256 rows x 64 k (8 lanes per 128B row seg)
  const int bn = t >> 3, bk8 = (t & 7) * 8;

  const float* ap = x + (size_t)(m0 + arow) * K_DIM + kbase + ac4 * 4;
  const __bf16* bp = Wt + (size_t)bn * K_DIM + kbase + bk8;

  f32x4 areg[2];
  bf16x8 breg[8];

  // prologue: prefetch iter 0
  areg[0] = *(const f32x4*)(ap);
  areg[1] = *(const f32x4*)(ap + 32);
#pragma unroll
  for (int c = 0; c < 8; ++c) breg[c] = *(const bf16x8*)(bp + (size_t)c * 32 * K_DIM);

  f32x4 acc[2][4];
  const f32x4 zero = {0.f, 0.f, 0.f, 0.f};
#pragma unroll
  for (int i = 0; i < 2; ++i)
#pragma unroll
    for (int j = 0; j < 4; ++j) acc[i][j] = zero;

  for (int it = 0; it < NITER; ++it) {
    __syncthreads();  // previous MFMA phase done reading LDS
    // ---- commit prefetched regs to LDS (compiler waits vmcnt here, per-wave) ----
    {
      bf16x4 o0 = {(__bf16)areg[0][0], (__bf16)areg[0][1],
                   (__bf16)areg[0][2], (__bf16)areg[0][3]};
      bf16x4 o1 = {(__bf16)areg[1][0], (__bf16)areg[1][1],
                   (__bf16)areg[1][2], (__bf16)areg[1][3]};
      *(bf16x4*)(&As[arow * 72 + ac4 * 4]) = o0;
      *(bf16x4*)(&As[arow * 72 + ac4 * 4 + 32]) = o1;
    }
#pragma unroll
    for (int c = 0; c < 8; ++c)
      *(bf16x8*)(&Bs[(bn + c * 32) * 72 + bk8]) = breg[c];
    __syncthreads();  // LDS ready

    // ---- issue next iteration's global loads; they fly under the MFMAs ----
    if (it + 1 < NITER) {
      ap += BK;
      bp += BK;
      areg[0] = *(const f32x4*)(ap);
      areg[1] = *(const f32x4*)(ap + 32);
#pragma unroll
      for (int c = 0; c < 8; ++c) breg[c] = *(const bf16x8*)(bp + (size_t)c * 32 * K_DIM);
    }

    // ---- 16 MFMAs per wave ----
#pragma unroll
    for (int ks = 0; ks < 2; ++ks) {
      const int kb = ks * 32 + q * 8;
      bf16x8 a[2], b[4];
#pragma unroll
      for (int i = 0; i < 2; ++i)
        a[i] = *(const bf16x8*)(&As[(i * 16 + la) * 72 + kb]);
#pragma unroll
      for (int j = 0; j < 4; ++j)
        b[j] = *(const bf16x8*)(&Bs[(w * 64 + j * 16 + la) * 72 + kb]);
#pragma unroll
      for (int i = 0; i < 2; ++i)
#pragma unroll
        for (int j = 0; j < 4; ++j)
          acc[i][j] = __builtin_amdgcn_mfma_f32_16x16x32_bf16(a[i], b[j], acc[i][j], 0, 0, 0);
    }
  }

  // ---- epilogue: bf16 partials (C/D layout: col=lane&15, row=quad*4+reg) ----
  __bf16* pbase = part + (size_t)ysplit * ((size_t)M_DIM * N_DIM);
#pragma unroll
  for (int i = 0; i < 2; ++i) {
    int r0 = m0 + i * 16 + q * 4;
#pragma unroll
    for (int j = 0; j < 4; ++j) {
      int c = w * 64 + j * 16 + la;
#pragma unroll
      for (int r = 0; r < 4; ++r)
        pbase[(size_t)(r0 + r) * N_DIM + c] = (__bf16)acc[i][j][r];
    }
  }
}

// ---------------- reduce partials + exact fp32 bit-flip correction + bias ----------------
__global__ __launch_bounds__(256) void reduce_kernel(const __bf16* __restrict__ part,
                                                     const float* __restrict__ x,
                                                     const float* __restrict__ W,
                                                     const float* __restrict__ bvec,
                                                     const float* __restrict__ coeffp,
                                                     const int* __restrict__ idx,
                                                     const int* __restrict__ bp,
                                                     float* __restrict__ out) {
  const int row = blockIdx.x;
  const int o = threadIdx.x;
  const int iv = idx[row];
  const float g = x[(size_t)row * K_DIM + iv];
  const int bits = __float_as_int(g) ^ (1 << bp[row]);
  const float upd = __int_as_float(bits) - g;  // swap_sim(g) - g, exact fp32
  const float coeff = coeffp[0];
  const size_t off = (size_t)row * N_DIM + o;
  float sum = 0.f;
#pragma unroll
  for (int s = 0; s < SPLIT; ++s)
    sum += (float)part[(size_t)s * ((size_t)M_DIM * N_DIM) + off];
  out[off] = sum + coeff * upd * W[(size_t)iv * N_DIM + o] + bvec[o];
}

extern "C" void kernel_launch(void* const* d_in, const int* in_sizes, int n_in,
                              void* d_out, int out_size, void* d_ws, size_t ws_size,
                              hipStream_t stream) {
  const float* x = (const float*)d_in[0];
  const float* W = (const float*)d_in[1];
  const float* b = (const float*)d_in[2];
  const float* coeff = (const float*)d_in[3];
  const int* idx = (const int*)d_in[4];
  const int* bp = (const int*)d_in[5];
  float* out = (float*)d_out;

  __bf16* Wt = (__bf16*)d_ws;
  const size_t wt_bytes = (size_t)K_DIM * N_DIM * 2;  // 8 MiB
  __bf16* part = (__bf16*)((char*)d_ws + wt_bytes);   // 8 x 2 MiB bf16 partials

  hipLaunchKernelGGL(wt_kernel, dim3(K_DIM / 64, N_DIM / 64), dim3(256), 0, stream, W, Wt);
  hipLaunchKernelGGL(gemm_kernel, dim3((M_DIM / BM) * SPLIT), dim3(256), 0, stream,
                     x, Wt, part);
  hipLaunchKernelGGL(reduce_kernel, dim3(M_DIM), dim3(256), 0, stream,
                     part, x, W, b, coeff, idx, bp, out);
}

// Round 7
// 404.499 us; speedup vs baseline: 1.0443x; 1.0443x over previous
//
#include <hip/hip_runtime.h>

#define M_DIM 4096
#define K_DIM 16384
#define N_DIM 256
#define SPLIT 8
#define BK 64
#define KSLICE (K_DIM / SPLIT)
#define NITER (KSLICE / BK)  // 32

typedef __bf16 bf16x8 __attribute__((ext_vector_type(8)));
typedef __bf16 bf16x4 __attribute__((ext_vector_type(4)));
typedef float f32x4 __attribute__((ext_vector_type(4)));

// ---------------- W transpose + convert: Wt[n][k] = bf16(W[k][n]) ----------------
__global__ __launch_bounds__(256) void wt_kernel(const float* __restrict__ W,
                                                 __bf16* __restrict__ Wt) {
  __shared__ float tile[64][65];
  const int k0 = blockIdx.x * 64, n0 = blockIdx.y * 64;
  const int t = threadIdx.x;
#pragma unroll
  for (int r = 0; r < 4; ++r) {
    int idx4 = r * 256 + t;
    int kr = idx4 >> 4, c4 = idx4 & 15;
    f32x4 v = *(const f32x4*)(W + (size_t)(k0 + kr) * N_DIM + n0 + c4 * 4);
#pragma unroll
    for (int j = 0; j < 4; ++j) tile[kr][c4 * 4 + j] = v[j];
  }
  __syncthreads();
#pragma unroll
  for (int r = 0; r < 4; ++r) {
    int nr = (t >> 4) + r * 16, k4 = t & 15;
    bf16x4 o;
#pragma unroll
    for (int j = 0; j < 4; ++j) o[j] = (__bf16)tile[k4 * 4 + j][nr];
    *(bf16x4*)(Wt + (size_t)(n0 + nr) * K_DIM + k0 + k4 * 4) = o;
  }
}

// ---------------- Main MFMA GEMM: round-5 winner, UNCHANGED (404.2 us base) --------
// BM=64, BN=256, BK=64, 256 thr = 4 waves; wave w owns 64m x 64n at n=w*64.
// XCD pin (T1, protected): split = bid & 7, 512 % 8 == 0 -> bijective; each XCD's
// B working set is its private 1 MiB Wt slice (L2-resident, reused 64x).
__global__ __launch_bounds__(256, 3) void gemm_kernel(const float* __restrict__ x,
                                                      const __bf16* __restrict__ Wt,
                                                      __bf16* __restrict__ part) {
  __shared__ __bf16 As[64 * 72];
  __shared__ __bf16 Bs[256 * 72];

  const int t = threadIdx.x;
  const int l = t & 63;
  const int w = t >> 6;
  const int la = l & 15, q = l >> 4;
  const int bid = blockIdx.x;
  const int ysplit = bid & 7;           // -> XCD ysplit (round-robin dispatch)
  const int m0 = (bid >> 3) * 64;
  const int kbase = ysplit * KSLICE;

  const int arow = t >> 4, ac4 = t & 15;
  const int bn = t >> 3, bk8 = (t & 7) * 8;

  const float* ap = x + (size_t)(m0 + arow) * K_DIM + kbase + ac4 * 4;
  const __bf16* bp = Wt + (size_t)bn * K_DIM + kbase + bk8;

  f32x4 areg[4];
  bf16x8 breg[8];

#pragma unroll
  for (int r = 0; r < 4; ++r) areg[r] = *(const f32x4*)(ap + (size_t)r * 16 * K_DIM);
#pragma unroll
  for (int c = 0; c < 8; ++c) breg[c] = *(const bf16x8*)(bp + (size_t)c * 32 * K_DIM);

  f32x4 acc[4][4];
  const f32x4 zero = {0.f, 0.f, 0.f, 0.f};
#pragma unroll
  for (int i = 0; i < 4; ++i)
#pragma unroll
    for (int j = 0; j < 4; ++j) acc[i][j] = zero;

  for (int it = 0; it < NITER; ++it) {
    __syncthreads();  // previous MFMA phase done reading LDS
#pragma unroll
    for (int r = 0; r < 4; ++r) {
      bf16x4 o = {(__bf16)areg[r][0], (__bf16)areg[r][1],
                  (__bf16)areg[r][2], (__bf16)areg[r][3]};
      *(bf16x4*)(&As[(arow + r * 16) * 72 + ac4 * 4]) = o;
    }
#pragma unroll
    for (int c = 0; c < 8; ++c)
      *(bf16x8*)(&Bs[(bn + c * 32) * 72 + bk8]) = breg[c];
    __syncthreads();  // LDS ready

    if (it + 1 < NITER) {
      ap += BK;
      bp += BK;
#pragma unroll
      for (int r = 0; r < 4; ++r) areg[r] = *(const f32x4*)(ap + (size_t)r * 16 * K_DIM);
#pragma unroll
      for (int c = 0; c < 8; ++c) breg[c] = *(const bf16x8*)(bp + (size_t)c * 32 * K_DIM);
    }

#pragma unroll
    for (int ks = 0; ks < 2; ++ks) {
      const int kb = ks * 32 + q * 8;
      bf16x8 a[4], b[4];
#pragma unroll
      for (int i = 0; i < 4; ++i)
        a[i] = *(const bf16x8*)(&As[(i * 16 + la) * 72 + kb]);
#pragma unroll
      for (int j = 0; j < 4; ++j)
        b[j] = *(const bf16x8*)(&Bs[(w * 64 + j * 16 + la) * 72 + kb]);
#pragma unroll
      for (int i = 0; i < 4; ++i)
#pragma unroll
        for (int j = 0; j < 4; ++j)
          acc[i][j] = __builtin_amdgcn_mfma_f32_16x16x32_bf16(a[i], b[j], acc[i][j], 0, 0, 0);
    }
  }

  __bf16* pbase = part + (size_t)ysplit * ((size_t)M_DIM * N_DIM);
#pragma unroll
  for (int i = 0; i < 4; ++i) {
    int r0 = m0 + i * 16 + q * 4;
#pragma unroll
    for (int j = 0; j < 4; ++j) {
      int c = w * 64 + j * 16 + la;
#pragma unroll
      for (int r = 0; r < 4; ++r)
        pbase[(size_t)(r0 + r) * N_DIM + c] = (__bf16)acc[i][j][r];
    }
  }
}

// ---------------- reduce: vectorized (G13) + 8 rows/block ----------------
// Was: 4096 blocks x 1 row, 8 scalar 2B bf16 loads/thread (launch+latency bound).
// Now: 512 blocks x 8 rows; thread = (row tr = t>>5, colgroup tc = t&31) owns 8 cols;
// partials loaded as bf16x8 (32 thr x 16B = 512B contiguous per split), W/bias/out
// as f32x4 pairs. Per-element summation order unchanged (s=0..7) -> same numerics.
__global__ __launch_bounds__(256) void reduce_kernel(const __bf16* __restrict__ part,
                                                     const float* __restrict__ x,
                                                     const float* __restrict__ W,
                                                     const float* __restrict__ bvec,
                                                     const float* __restrict__ coeffp,
                                                     const int* __restrict__ idx,
                                                     const int* __restrict__ bp,
                                                     float* __restrict__ out) {
  const int t = threadIdx.x;
  const int tr = t >> 5;                 // row within this block's 8-row group
  const int tc = t & 31;                 // column group (8 cols each)
  const int row = blockIdx.x * 8 + tr;
  const int c0 = tc * 8;
  const int iv = idx[row];
  const float g = x[(size_t)row * K_DIM + iv];
  const int bits = __float_as_int(g) ^ (1 << bp[row]);
  const float upd = __int_as_float(bits) - g;  // swap_sim(g) - g, exact fp32
  const float cu = coeffp[0] * upd;

  const size_t off = (size_t)row * N_DIM + c0;
  float sum[8] = {0.f, 0.f, 0.f, 0.f, 0.f, 0.f, 0.f, 0.f};
#pragma unroll
  for (int s = 0; s < SPLIT; ++s) {
    bf16x8 v = *(const bf16x8*)(part + (size_t)s * ((size_t)M_DIM * N_DIM) + off);
#pragma unroll
    for (int e = 0; e < 8; ++e) sum[e] += (float)v[e];
  }

  const float* wrow = W + (size_t)iv * N_DIM + c0;
  f32x4 w0 = *(const f32x4*)(wrow);
  f32x4 w1 = *(const f32x4*)(wrow + 4);
  f32x4 b0 = *(const f32x4*)(bvec + c0);
  f32x4 b1 = *(const f32x4*)(bvec + c0 + 4);
  f32x4 o0, o1;
#pragma unroll
  for (int e = 0; e < 4; ++e) {
    o0[e] = sum[e] + cu * w0[e] + b0[e];
    o1[e] = sum[e + 4] + cu * w1[e] + b1[e];
  }
  *(f32x4*)(out + off) = o0;
  *(f32x4*)(out + off + 4) = o1;
}

extern "C" void kernel_launch(void* const* d_in, const int* in_sizes, int n_in,
                              void* d_out, int out_size, void* d_ws, size_t ws_size,
                              hipStream_t stream) {
  const float* x = (const float*)d_in[0];
  const float* W = (const float*)d_in[1];
  const float* b = (const float*)d_in[2];
  const float* coeff = (const float*)d_in[3];
  const int* idx = (const int*)d_in[4];
  const int* bp = (const int*)d_in[5];
  float* out = (float*)d_out;

  __bf16* Wt = (__bf16*)d_ws;
  const size_t wt_bytes = (size_t)K_DIM * N_DIM * 2;  // 8 MiB
  __bf16* part = (__bf16*)((char*)d_ws + wt_bytes);   // 8 x 2 MiB bf16 partials

  hipLaunchKernelGGL(wt_kernel, dim3(K_DIM / 64, N_DIM / 64), dim3(256), 0, stream, W, Wt);
  hipLaunchKernelGGL(gemm_kernel, dim3((M_DIM / 64) * SPLIT), dim3(256), 0, stream,
                     x, Wt, part);
  hipLaunchKernelGGL(reduce_kernel, dim3(M_DIM / 8), dim3(256), 0, stream,
                     part, x, W, b, coeff, idx, bp, out);
}